// Round 18
// baseline (572.345 us; speedup 1.0000x reference)
//
#include <hip/hip_runtime.h>
#include <hip/hip_bf16.h>

// Problem constants
constexpr int B    = 4096;
constexpr int T    = 80;
constexpr int CTXN = 10;
constexpr int D    = 300;
constexpr int R    = 200;
constexpr int HA   = 100;
constexpr int TD   = 256;
constexpr int NTY  = 113;
constexpr int PL   = 3;
constexpr int NTOK = 250;
constexpr int CTX2 = 20;    // 2*CTX
constexpr int R2   = 400;   // 2R
constexpr int FEAT = 700;   // D + 2R

// padded layout constants
constexpr int XSB  = 320;   // x row stride (300 pad to 320)
constexpr int KH   = 256;   // h part of concat K (200 pad to 256)
constexpr int KW   = 576;   // total gate-GEMM K: [Wh 0..255 | Wx 256..575]
constexpr int NB   = 832;   // bundled gate cols: 13 rb * 64 (4 gates x 16 r)
constexpr int CTXS = 448;   // ctx row stride: [dir0 0..223 | dir1 224..447]
constexpr int DREG = 224;   // per-dir region width (cols)
constexpr int F1S  = 320;   // f1 row stride
constexpr int FBS  = 704;   // feat row stride (700 -> 704)
constexpr int FMS  = 128;   // fm col stride (100 -> 128)
constexpr int MX   = 2 * B * CTXN;  // 81920 x-rows (side-major)
constexpr int MB   = 32;    // batch rows per k_lstm block (2 blocks/CU target)

typedef __attribute__((ext_vector_type(8))) short bf16x8;
typedef __attribute__((ext_vector_type(4))) float f32x4;

__device__ __forceinline__ ushort f2bf(float f) {
    union { float f; uint32_t u; } x{f};
    uint32_t r = x.u + 0x7fff + ((x.u >> 16) & 1);
    return (ushort)(r >> 16);
}
__device__ __forceinline__ float bf2f(ushort u) {
    union { uint32_t u; float f; } x{(uint32_t)u << 16};
    return x.f;
}
// fast sigmoid/tanh via v_exp_f32 + v_rcp_f32 (exact at saturation)
__device__ __forceinline__ float fsig(float x) {
    return __builtin_amdgcn_rcpf(1.f + __expf(-x));
}
__device__ __forceinline__ float ftanh(float x) {
    return 1.f - 2.f * __builtin_amdgcn_rcpf(__expf(2.f * x) + 1.f);
}

#define GLD_LDS(g, l) __builtin_amdgcn_global_load_lds( \
    (const __attribute__((address_space(1))) void*)(g), \
    (__attribute__((address_space(3))) void*)(l), 16, 0, 0)
// NT variant: single-touch streams must not evict L2-resident weights
#define GLD_LDS_NT(g, l) __builtin_amdgcn_global_load_lds( \
    (const __attribute__((address_space(1))) void*)(g), \
    (__attribute__((address_space(3))) void*)(l), 16, 0, 2)

// ---------------------------------------------------------------------------
// weight prep: Wcat[dir][n' 832][k 576] bf16 (k = [Wh 256 | Wx 320]) + bias
// n' = rb*64 + g*16 + ri  <->  original gate col = g*200 + rb*16 + ri
constexpr int NWC = 2 * NB * KW;
__global__ void k_prepw3(const float* __restrict__ Wx_f, const float* __restrict__ Wh_f,
                         const float* __restrict__ bf_, const float* __restrict__ Wx_b,
                         const float* __restrict__ Wh_b, const float* __restrict__ bb_,
                         ushort* __restrict__ Wcat, float* __restrict__ biasb) {
    int gid = blockIdx.x * blockDim.x + threadIdx.x;
    if (gid < NWC) {
        int k = gid % KW;
        int q = gid / KW;
        int np = q % NB, dir = q / NB;
        int rb = np >> 6, g = (np >> 4) & 3, ri = np & 15;
        int r = rb * 16 + ri, col = g * 200 + r;
        float v = 0.f;
        if (r < R) {
            if (k < KH) {
                if (k < R) v = (dir ? Wh_b : Wh_f)[(size_t)k * 800 + col];
            } else {
                int kx = k - KH;
                if (kx < D) v = (dir ? Wx_b : Wx_f)[(size_t)kx * 800 + col];
            }
        }
        Wcat[gid] = f2bf(v);
    } else if (gid < NWC + 2 * NB) {
        int t = gid - NWC;
        int np = t % NB, dirb = t / NB;
        int rb = np >> 6, g = (np >> 4) & 3, ri = np & 15;
        int r = rb * 16 + ri, col = g * 200 + r;
        biasb[t] = (r < R) ? (dirb ? bb_ : bf_)[col] : 0.f;
    }
}

// h1t[n 128][k 448] — dual-region ctx layout:
// ctx col c<224 -> h1 row c (c<200), c>=224 -> h1 row 200+(c-224) (c-224<200)
__global__ void k_preph1(const float* __restrict__ h1, ushort* __restrict__ h1t) {
    int gid = blockIdx.x * blockDim.x + threadIdx.x;
    if (gid >= FMS * CTXS) return;
    int k = gid % CTXS, n = gid / CTXS;
    float v = 0.f;
    if (n < HA) {
        if (k < DREG) {
            if (k < R) v = h1[(size_t)k * HA + n];
        } else {
            int r2 = k - DREG;
            if (r2 < R) v = h1[(size_t)(R + r2) * HA + n];
        }
    }
    h1t[gid] = f2bf(v);
}
// h_mt[n 128][k 320]
__global__ void k_prephm(const float* __restrict__ h_m, ushort* __restrict__ h_mt) {
    int gid = blockIdx.x * blockDim.x + threadIdx.x;
    if (gid >= FMS * F1S) return;
    int k = gid % F1S, n = gid / F1S;
    float v = (n < HA && k < D) ? h_m[(size_t)k * HA + n] : 0.f;
    h_mt[gid] = f2bf(v);
}
// dWt[n 256][k 704]
__global__ void k_prepdw(const float* __restrict__ dW, ushort* __restrict__ dWt) {
    int gid = blockIdx.x * blockDim.x + threadIdx.x;
    if (gid >= TD * FBS) return;
    int k = gid % FBS, n = gid / FBS;
    float v = (k < FEAT) ? dW[(size_t)k * TD + n] : 0.f;
    dWt[gid] = f2bf(v);
}

// ---------------------------------------------------------------------------
// gather context word vectors -> xb[row = side*40960 + b*10 + t][320] bf16
__global__ void k_gatherb(const int* __restrict__ idxL, const int* __restrict__ idxR,
                          const int* __restrict__ input_data,
                          const float* __restrict__ we,
                          ushort* __restrict__ xb) {
    int row = blockIdx.x * 4 + (threadIdx.x >> 6);
    int lane = threadIdx.x & 63;
    if (row >= MX) return;
    int side = row / (B * CTXN);
    int bt = row % (B * CTXN);
    int idx = (side ? idxR : idxL)[bt];
    int w = (idx >= 0 && idx < B * T) ? input_data[idx] : -1;
    ushort* dst = xb + (size_t)row * XSB;
    if (lane < XSB / 8) {
        int e0 = lane * 8;
        ushort tmp[8];
        #pragma unroll
        for (int j = 0; j < 8; ++j) {
            int e = e0 + j;
            float f = (w >= 0 && e < D) ? we[(size_t)w * D + e] : 0.f;
            tmp[j] = f2bf(f);
        }
        *reinterpret_cast<bf16x8*>(dst + e0) = *reinterpret_cast<bf16x8*>(tmp);
    }
}

// ---------------------------------------------------------------------------
// f1 = mean of mention vectors -> featb[:,0:300] and f1b[:,0:320] (bf16)
__global__ void k_f1(const int* __restrict__ ment_idx,
                     const float* __restrict__ ment_lent,
                     const int* __restrict__ input_data,
                     const float* __restrict__ we,
                     ushort* __restrict__ featb, ushort* __restrict__ f1b) {
    int b = blockIdx.x;
    __shared__ int wrow[5];
    if (threadIdx.x < 5) {
        int idx = ment_idx[b * 5 + threadIdx.x];
        wrow[threadIdx.x] = (idx >= 0 && idx < B * T) ? input_data[idx] : -1;
    }
    __syncthreads();
    float inv = 1.0f / ment_lent[b];
    for (int d = threadIdx.x; d < F1S; d += blockDim.x) {
        float s = 0.f;
        if (d < D) {
            #pragma unroll
            for (int j = 0; j < 5; ++j) {
                int w = wrow[j];
                if (w >= 0) s += we[(size_t)w * D + d];
            }
            s *= inv;
        }
        ushort u = f2bf(s);
        if (d < D) featb[(size_t)b * FBS + d] = u;
        f1b[(size_t)b * F1S + d] = u;
    }
}

// ---------------------------------------------------------------------------
// Generic MFMA GEMM: C[M x N] = epi(A[M x K]bf16 @ Bt[N x K]bf16^T)
// BM=128, BN=64, BK=64.  MODE 1: bias+relu -> fp32.  MODE 3: plain fp32.
template<int MODE>
__global__ __launch_bounds__(256) void k_mfma(
    const ushort* __restrict__ A, int lda,
    const ushort* __restrict__ Bt, int ldb,
    float* __restrict__ C, int ldc, int K,
    const float* __restrict__ aux) {
    __shared__ __align__(16) ushort As[128 * 64];
    __shared__ __align__(16) ushort Bs[64 * 64];
    int tid = threadIdx.x, wave = tid >> 6, lane = tid & 63;
    int m0 = blockIdx.y * 128, n0 = blockIdx.x * 64;
    int wr = wave >> 1, wc = wave & 1;
    f32x4 acc[4][2] = {};

    for (int k0 = 0; k0 < K; k0 += 64) {
        #pragma unroll
        for (int p = 0; p < 4; ++p) {
            int chunk = p * 4 + wave;
            int row = chunk * 8 + (lane >> 3);
            int ss = (lane & 7) ^ (row & 7);
            GLD_LDS(A + (size_t)(m0 + row) * lda + k0 + ss * 8, As + chunk * 512);
        }
        #pragma unroll
        for (int p = 0; p < 2; ++p) {
            int chunk = p * 4 + wave;
            int row = chunk * 8 + (lane >> 3);
            int ss = (lane & 7) ^ (row & 7);
            GLD_LDS(Bt + (size_t)(n0 + row) * ldb + k0 + ss * 8, Bs + chunk * 512);
        }
        __syncthreads();
        #pragma unroll
        for (int kk = 0; kk < 2; ++kk) {
            bf16x8 a[4], bf[2];
            #pragma unroll
            for (int m = 0; m < 4; ++m) {
                int r = wr * 64 + m * 16 + (lane & 15);
                int ss = (kk * 4 + (lane >> 4)) ^ (r & 7);
                a[m] = *(const bf16x8*)&As[r * 64 + ss * 8];
            }
            #pragma unroll
            for (int n = 0; n < 2; ++n) {
                int r = wc * 32 + n * 16 + (lane & 15);
                int ss = (kk * 4 + (lane >> 4)) ^ (r & 7);
                bf[n] = *(const bf16x8*)&Bs[r * 64 + ss * 8];
            }
            #pragma unroll
            for (int m = 0; m < 4; ++m)
                #pragma unroll
                for (int n = 0; n < 2; ++n)
                    acc[m][n] = __builtin_amdgcn_mfma_f32_16x16x32_bf16(a[m], bf[n], acc[m][n], 0, 0, 0);
        }
        __syncthreads();
    }
    #pragma unroll
    for (int m = 0; m < 4; ++m) {
        #pragma unroll
        for (int n = 0; n < 2; ++n) {
            int c = n0 + wc * 32 + n * 16 + (lane & 15);
            #pragma unroll
            for (int j = 0; j < 4; ++j) {
                int rr = m0 + wr * 64 + m * 16 + (lane >> 4) * 4 + j;
                float v = acc[m][n][j];
                if (MODE == 1) v = fmaxf(v + aux[c], 0.f);
                C[(size_t)rr * ldc + c] = v;
            }
        }
    }
}

// ---------------------------------------------------------------------------
// Persistent fused BiLSTM: 512 blocks (target 2/CU) x 512 threads (8 waves).
// r18 = r17 with 16-col QUARTER-tile weight staging (one gate per load):
// wS shrinks 32K -> 16K, total LDS 69.5K -> 53.4K <= 64K/block so two
// blocks can co-reside (r17's 69.5K blocked co-residency -> serialized
// passes at 22% occupancy). 2-deep quarter ring, steady-state vmcnt(1),
// issue-after-consume. Keeps: dir-segregated XCD map + dual-region ctx,
// NT x staging, fast cell math, r13-proven barrier structure.
#define WQ(KT2, Q2, BUF2) { \
    int nl = lane >> 2, c8s = lane & 3; \
    int c8 = c8s ^ ((nl >> 1) & 3); \
    GLD_LDS(wb + (size_t)((Q2) * 16 + nl) * KW + (KT2) * 32 + c8 * 8, \
            wSf[wave] + (BUF2) * 512); \
}

__global__ __launch_bounds__(512, 1) void k_lstm(
    const ushort* __restrict__ xb,       // [MX][320]
    const ushort* __restrict__ Wcat,     // [2][832][576]
    const float* __restrict__ biasb,     // [2][832]
    const float* __restrict__ lentL, const float* __restrict__ lentR,
    ushort* __restrict__ ctxb) {         // [B][20][448] dual-region
    __shared__ __align__(16) ushort hS[MB * 256];      // 16K swizzled h state
    __shared__ __align__(16) ushort xS[MB * 320];      // 20K swizzled x tile
    __shared__ __align__(16) ushort wSf[8][1024];      // 16K W quarter ring / h stage
    __shared__ int lenS[MB];
    __shared__ int xrowS[CTXN][MB];

    const int tid = threadIdx.x, wave = tid >> 6, lane = tid & 63;
    const int bid = blockIdx.x, xcd = bid & 7;
    const int dir = xcd >> 2;                     // XCD 0-3 -> dir0, 4-7 -> dir1
    const int idx = (xcd & 3) * 64 + (bid >> 3);  // bijective [0,256) per dir
    const int side = idx >> 7, rg = idx & 127;
    const int b0 = rg * MB;
    const ushort* Wd = Wcat + (size_t)dir * NB * KW;
    const int rl = lane & 15, ch = lane >> 4;

    if (tid < MB) {
        int b = b0 + tid;
        int len = (int)((side ? lentR : lentL)[b]);
        len = min(max(len, 0), CTXN);
        lenS[tid] = len;
        for (int s = 0; s < CTXN; ++s) {
            int tt = dir ? ((s < len) ? (len - 1 - s) : s) : s;
            xrowS[s][tid] = (side * (B * CTXN) + b * CTXN + tt) * XSB;
        }
    }
    // zero h state (MB*256 ushorts = 1024 uint4)
    {
        uint4 zz{0, 0, 0, 0};
        for (int i = tid; i < MB * 256 / 8; i += 512)
            reinterpret_cast<uint4*>(hS)[i] = zz;
    }

    const int nrb = (wave + 8 < 13) ? 2 : 1;
    float bias_[2][4];
    #pragma unroll
    for (int g = 0; g < 4; ++g) {
        bias_[0][g] = biasb[dir * NB + wave * 64 + g * 16 + rl];
        bias_[1][g] = (nrb > 1) ? biasb[dir * NB + (wave + 8) * 64 + g * 16 + rl] : 0.f;
    }
    float cst[2][8];
    #pragma unroll
    for (int i = 0; i < 2; ++i)
        #pragma unroll
        for (int j = 0; j < 8; ++j) cst[i][j] = 0.f;

    __syncthreads();

    // stage x tile for s=0: MB*320 ushorts = 20 chunks of 512 (NT)
    for (int c2 = wave; c2 < 20; c2 += 8) {
        int p = c2 * 64 + lane;
        int row = p / 40, c8s = p - row * 40;
        int c8 = c8s ^ (row & 7);
        GLD_LDS_NT(xb + xrowS[0][row] + c8 * 8, xS + c2 * 512);
    }
    __syncthreads();

    float hnew[2][8];

    for (int s = 0; s < CTXN; ++s) {
        const int ktstart = (s == 0) ? 8 : 0;   // h == 0 at s=0: skip Wh part
        #pragma unroll
        for (int rbi = 0; rbi < 2; ++rbi) {
            if (rbi < nrb) {
                const int rb = rbi ? (wave + 8) : wave;
                const ushort* wb = Wd + (size_t)rb * 64 * KW;
                f32x4 acc[2][4] = {};
                // prologue: first two quarters -> buf0, buf1
                WQ(ktstart, 0, 0);
                WQ(ktstart, 1, 1);
                const int roff = (rl * 4 + (ch ^ ((rl >> 1) & 3))) * 8;
                for (int kt = ktstart; kt < 18; ++kt) {
                    // A fragments for this kt (shared by the 4 quarters)
                    bf16x8 af[2];
                    {
                        const ushort* abase; int astr, kof;
                        if (kt < 8) { abase = hS; astr = 256; kof = kt * 4; }
                        else        { abase = xS; astr = 320; kof = (kt - 8) * 4; }
                        #pragma unroll
                        for (int m = 0; m < 2; ++m) {
                            int row = m * 16 + rl;
                            int g = (kof + ch) ^ (row & 7);
                            af[m] = *reinterpret_cast<const bf16x8*>(&abase[row * astr + g * 8]);
                        }
                    }
                    #pragma unroll
                    for (int q = 0; q < 4; ++q) {
                        // quarter abs = (kt-ktstart)*4 + q; buffer parity = q&1
                        if (kt < 17 || q < 3) { asm volatile("s_waitcnt vmcnt(1)" ::: "memory"); }
                        else                  { asm volatile("s_waitcnt vmcnt(0)" ::: "memory"); }
                        const ushort* wq = wSf[wave] + (q & 1) * 512;
                        bf16x8 bq = *reinterpret_cast<const bf16x8*>(&wq[roff]);
                        // issue quarter abs+2 into the same buffer
                        {
                            int q2 = q + 2;
                            int nkt = kt + (q2 >> 2);
                            int nq = q2 & 3;
                            if (nkt < 18) { WQ(nkt, nq, (q & 1)); }
                        }
                        acc[0][q] = __builtin_amdgcn_mfma_f32_16x16x32_bf16(af[0], bq, acc[0][q], 0, 0, 0);
                        acc[1][q] = __builtin_amdgcn_mfma_f32_16x16x32_bf16(af[1], bq, acc[1][q], 0, 0, 0);
                    }
                }
                // LSTM cell (fast sigmoid/tanh) — regs only
                #pragma unroll
                for (int m = 0; m < 2; ++m) {
                    #pragma unroll
                    for (int j = 0; j < 4; ++j) {
                        int row = m * 16 + ch * 4 + j;
                        float gi = acc[m][0][j] + bias_[rbi][0];
                        float gf = acc[m][1][j] + bias_[rbi][1];
                        float gg = acc[m][2][j] + bias_[rbi][2];
                        float go = acc[m][3][j] + bias_[rbi][3];
                        float si = fsig(gi), sf = fsig(gf), so = fsig(go);
                        float cn = sf * cst[rbi][m * 4 + j] + si * ftanh(gg);
                        float hn = so * ftanh(cn);
                        if (s < lenS[row]) cst[rbi][m * 4 + j] = cn;
                        hnew[rbi][m * 4 + j] = hn;
                    }
                }
            }
        }
        // barrier1: all LDS reads of hS/xS/wSf complete (weight vmem drained)
        asm volatile("s_waitcnt lgkmcnt(0)" ::: "memory");
        __builtin_amdgcn_s_barrier();

        // write h_new -> hS (masked) + stage (h or 0) -> wSf[wave] [32][32]
        #pragma unroll
        for (int rbi = 0; rbi < 2; ++rbi) {
            if (rbi < nrb) {
                const int rb = wave + rbi * 8;
                const int r = rb * 16 + rl;
                #pragma unroll
                for (int m = 0; m < 2; ++m) {
                    #pragma unroll
                    for (int j = 0; j < 4; ++j) {
                        int row = m * 16 + ch * 4 + j;
                        bool live = (s < lenS[row]);
                        ushort hv = f2bf(live ? hnew[rbi][m * 4 + j] : 0.f);
                        wSf[wave][row * 32 + rbi * 16 + rl] = hv;
                        if (live && r < R)
                            hS[row * 256 + (((r >> 3) ^ (row & 7)) << 3) + (r & 7)] = hv;
                    }
                }
            }
        }
        // stage x tile for next step (NT; in flight until barrier3)
        if (s + 1 < CTXN) {
            for (int c2 = wave; c2 < 20; c2 += 8) {
                int p = c2 * 64 + lane;
                int row = p / 40, c8s = p - row * 40;
                int c8 = c8s ^ (row & 7);
                GLD_LDS_NT(xb + xrowS[s + 1][row] + c8 * 8, xS + c2 * 512);
            }
        }
        // barrier2: stage + hS visible (x loads may still be in flight)
        asm volatile("s_waitcnt lgkmcnt(0)" ::: "memory");
        __builtin_amdgcn_s_barrier();

        // cooperative ctx write: MB rows x 28 granules of 16B into this dir's
        // 448B-aligned region; granules 26/27 (cols 208-223) are pad zeros.
        for (int i = tid; i < MB * 28; i += 512) {
            int row = i / 28, g = i - row * 28;
            int len = lenS[row];
            int tp = (s < len) ? (dir ? (len - 1 - s) : s) : s;
            bf16x8 v{};
            if (g < 26) {
                int rb2 = g >> 1;
                int w = rb2 & 7, rbi = rb2 >> 3;
                int off = (g & 1) * 8;
                v = *reinterpret_cast<const bf16x8*>(&wSf[w][row * 32 + rbi * 16 + off]);
            }
            *reinterpret_cast<bf16x8*>(
                ctxb + ((size_t)(b0 + row) * CTX2 + side * CTXN + tp) * CTXS + dir * DREG + g * 8) = v;
        }
        // barrier3: full drain (x staged, stores issued, wSf free for reuse)
        asm volatile("s_waitcnt vmcnt(0) lgkmcnt(0)" ::: "memory");
        __builtin_amdgcn_s_barrier();
    }
}

// ---------------------------------------------------------------------------
// att-score GEMM: scores[row] = relu(ctx[row]@h1 + fm[row/20]) . h2
// grid (MX/128), BM=128, BN=128(full), K=448  (dual-region K handled by h1t)
__global__ __launch_bounds__(256) void k_attsc(
    const ushort* __restrict__ ctxb, const ushort* __restrict__ h1t,
    const float* __restrict__ fm, const float* __restrict__ h2,
    float* __restrict__ scores) {
    __shared__ __align__(16) ushort As[128 * 64];
    __shared__ __align__(16) ushort Bs[128 * 64];
    __shared__ float sred[128][2];
    __shared__ float h2s[128];
    int tid = threadIdx.x, wave = tid >> 6, lane = tid & 63;
    int m0 = blockIdx.x * 128;
    if (tid < 128) h2s[tid] = (tid < HA) ? h2[tid] : 0.f;
    int wr = wave >> 1, wc = wave & 1;
    f32x4 acc[4][4] = {};

    for (int k0 = 0; k0 < CTXS; k0 += 64) {
        #pragma unroll
        for (int p = 0; p < 4; ++p) {
            int chunk = p * 4 + wave;
            int row = chunk * 8 + (lane >> 3);
            int ss = (lane & 7) ^ (row & 7);
            GLD_LDS(ctxb + (size_t)(m0 + row) * CTXS + k0 + ss * 8, As + chunk * 512);
        }
        #pragma unroll
        for (int p = 0; p < 4; ++p) {
            int chunk = p * 4 + wave;
            int row = chunk * 8 + (lane >> 3);
            int ss = (lane & 7) ^ (row & 7);
            GLD_LDS(h1t + (size_t)row * CTXS + k0 + ss * 8, Bs + chunk * 512);
        }
        __syncthreads();
        #pragma unroll
        for (int kk = 0; kk < 2; ++kk) {
            bf16x8 a[4], bf[4];
            #pragma unroll
            for (int m = 0; m < 4; ++m) {
                int r = wr * 64 + m * 16 + (lane & 15);
                int ss = (kk * 4 + (lane >> 4)) ^ (r & 7);
                a[m] = *(const bf16x8*)&As[r * 64 + ss * 8];
            }
            #pragma unroll
            for (int n = 0; n < 4; ++n) {
                int r = wc * 64 + n * 16 + (lane & 15);
                int ss = (kk * 4 + (lane >> 4)) ^ (r & 7);
                bf[n] = *(const bf16x8*)&Bs[r * 64 + ss * 8];
            }
            #pragma unroll
            for (int m = 0; m < 4; ++m)
                #pragma unroll
                for (int n = 0; n < 4; ++n)
                    acc[m][n] = __builtin_amdgcn_mfma_f32_16x16x32_bf16(a[m], bf[n], acc[m][n], 0, 0, 0);
        }
        __syncthreads();
    }
    #pragma unroll
    for (int m = 0; m < 4; ++m) {
        #pragma unroll
        for (int j = 0; j < 4; ++j) {
            int rl = wr * 64 + m * 16 + (lane >> 4) * 4 + j;
            int brow = (m0 + rl) / CTX2;
            float v = 0.f;
            #pragma unroll
            for (int n = 0; n < 4; ++n) {
                int c = wc * 64 + n * 16 + (lane & 15);
                float a = acc[m][n][j] + fm[(size_t)brow * FMS + c];
                v += fmaxf(a, 0.f) * h2s[c];
            }
            #pragma unroll
            for (int o = 1; o < 16; o <<= 1) v += __shfl_xor(v, o, 64);
            if ((lane & 15) == 0) sred[rl][wc] = v;
        }
    }
    __syncthreads();
    if (tid < 128) scores[m0 + tid] = sred[tid][0] + sred[tid][1];
}

// ---------------------------------------------------------------------------
// softmax over 20 scores + weighted ctx sum -> featb[:,300:700] (+pad zero)
// ctx col c<200 at region pos c; c>=200 at pos 224+(c-200)
__global__ void k_att2(const float* __restrict__ scores,
                       const ushort* __restrict__ ctxb,
                       ushort* __restrict__ featb) {
    int b = blockIdx.x;
    float sc[CTX2];
    #pragma unroll
    for (int t = 0; t < CTX2; ++t) sc[t] = scores[b * CTX2 + t];
    float mx = -1e30f;
    #pragma unroll
    for (int t = 0; t < CTX2; ++t) mx = fmaxf(mx, sc[t]);
    float w[CTX2], sum = 0.f;
    #pragma unroll
    for (int t = 0; t < CTX2; ++t) { w[t] = __expf(sc[t] - mx); sum += w[t]; }
    float inv = 1.f / sum;
    for (int col = threadIdx.x; col < R2; col += 256) {
        int pos = (col < R) ? col : col + (DREG - R);
        float acc = 0.f;
        #pragma unroll
        for (int t = 0; t < CTX2; ++t)
            acc += w[t] * bf2f(ctxb[((size_t)b * CTX2 + t) * CTXS + pos]);
        featb[(size_t)b * FBS + D + col] = f2bf(acc * inv);
    }
    if (threadIdx.x < FBS - FEAT)
        featb[(size_t)b * FBS + FEAT + threadIdx.x] = 0;
}

// ---------------------------------------------------------------------------
__device__ __forceinline__ float blk_sum_256(float v, float* red) {
    #pragma unroll
    for (int o = 32; o > 0; o >>= 1) v += __shfl_down(v, o, 64);
    int lane = threadIdx.x & 63, wid = threadIdx.x >> 6;
    if (lane == 0) red[wid] = v;
    __syncthreads();
    float t = red[0] + red[1] + red[2] + red[3];
    __syncthreads();
    return t;
}

__global__ void k_l2norm(float* __restrict__ x, int ncol) {
    int row = blockIdx.x;
    float* p = x + (size_t)row * ncol;
    __shared__ float red[4];
    float ss = 0.f;
    for (int c = threadIdx.x; c < ncol; c += 256) { float v = p[c]; ss += v * v; }
    float tot = blk_sum_256(ss, red);
    float scale = 1.f / sqrtf(fmaxf(tot, 1e-12f));
    for (int c = threadIdx.x; c < ncol; c += 256) p[c] *= scale;
}

__global__ void k_typenorm(const int* __restrict__ type_path,
                           const float* __restrict__ type_tok,
                           float* __restrict__ tnorm) {
    int y = blockIdx.x;
    int c = threadIdx.x;
    __shared__ float red[4];
    float s = 0.f;
    #pragma unroll
    for (int j = 0; j < PL; ++j) {
        int tk = type_path[y * PL + j];
        if (tk >= 0 && tk < NTOK) s += type_tok[(size_t)tk * TD + c];
    }
    float tot = blk_sum_256(s * s, red);
    float scale = 1.f / sqrtf(fmaxf(tot, 1e-12f));
    tnorm[(size_t)y * TD + c] = s * scale;
}

__global__ void k_final(const float* __restrict__ ent,
                        const float* __restrict__ tnorm,
                        float* __restrict__ out) {
    int b = blockIdx.x;
    __shared__ float es[TD];
    for (int c = threadIdx.x; c < TD; c += blockDim.x) es[c] = ent[(size_t)b * TD + c];
    __syncthreads();
    for (int y = threadIdx.x; y < NTY; y += blockDim.x) {
        const float* tn = tnorm + (size_t)y * TD;
        float acc = 0.f;
        #pragma unroll 4
        for (int k = 0; k < TD; ++k) acc += es[k] * tn[k];
        out[(size_t)b * NTY + y] = acc;
    }
}

// ---------------------------------------------------------------------------
static inline char* wsalloc(char*& p, size_t bytes) {
    char* r = p;
    p += (bytes + 255) & ~(size_t)255;
    return r;
}

extern "C" void kernel_launch(void* const* d_in, const int* in_sizes, int n_in,
                              void* d_out, int out_size, void* d_ws, size_t ws_size,
                              hipStream_t stream) {
    const int*   input_data       = (const int*)d_in[0];
    const int*   entMentIndex     = (const int*)d_in[1];
    const int*   entCtxLeftIndex  = (const int*)d_in[2];
    const int*   entCtxRightIndex = (const int*)d_in[3];
    const float* entMentLent      = (const float*)d_in[4];
    const float* ctxLeftLent      = (const float*)d_in[5];
    const float* ctxRightLent     = (const float*)d_in[6];
    const int*   type_path        = (const int*)d_in[7];
    const float* word_embed       = (const float*)d_in[8];
    const float* h_m              = (const float*)d_in[9];
    const float* h1               = (const float*)d_in[10];
    const float* h2               = (const float*)d_in[11];
    const float* Wx_f             = (const float*)d_in[12];
    const float* Wh_f             = (const float*)d_in[13];
    const float* b_f              = (const float*)d_in[14];
    const float* Wx_b             = (const float*)d_in[15];
    const float* Wh_b             = (const float*)d_in[16];
    const float* b_b              = (const float*)d_in[17];
    const float* dense_W          = (const float*)d_in[18];
    const float* dense_b          = (const float*)d_in[19];
    const float* type_tok         = (const float*)d_in[20];
    float* out = (float*)d_out;

    char* p = (char*)d_ws;
    ushort* xb    = (ushort*)wsalloc(p, (size_t)MX * XSB * 2);          // 52.4 MB
    ushort* ctxb  = (ushort*)wsalloc(p, (size_t)B * CTX2 * CTXS * 2);   // 73.4 MB
    ushort* featb = (ushort*)wsalloc(p, (size_t)B * FBS * 2);
    ushort* f1b   = (ushort*)wsalloc(p, (size_t)B * F1S * 2);
    float*  fm    = (float*) wsalloc(p, (size_t)B * FMS * 4);
    float*  scores= (float*) wsalloc(p, (size_t)MX * 4);
    float*  ent   = (float*) wsalloc(p, (size_t)B * TD * 4);
    float*  tnorm = (float*) wsalloc(p, (size_t)NTY * TD * 4);
    ushort* Wcat  = (ushort*)wsalloc(p, (size_t)2 * NB * KW * 2);       // 1.9 MB
    float*  biasb = (float*) wsalloc(p, (size_t)2 * NB * 4);
    ushort* h1t   = (ushort*)wsalloc(p, (size_t)FMS * CTXS * 2);
    ushort* h_mt  = (ushort*)wsalloc(p, (size_t)FMS * F1S * 2);
    ushort* dWt   = (ushort*)wsalloc(p, (size_t)TD * FBS * 2);

    // weight prep (no memsets — all consumed buffers fully written)
    {
        int tot = NWC + 2 * NB;
        k_prepw3<<<(tot + 255) / 256, 256, 0, stream>>>(Wx_f, Wh_f, b_f, Wx_b, Wh_b, b_b,
                                                        Wcat, biasb);
    }
    k_preph1<<<(FMS * CTXS + 255) / 256, 256, 0, stream>>>(h1, h1t);
    k_prephm<<<(FMS * F1S + 255) / 256, 256, 0, stream>>>(h_m, h_mt);
    k_prepdw<<<(TD * FBS + 255) / 256, 256, 0, stream>>>(dense_W, dWt);

    // gathers + f1
    k_gatherb<<<(MX + 3) / 4, 256, 0, stream>>>(entCtxLeftIndex, entCtxRightIndex,
                                                input_data, word_embed, xb);
    k_f1<<<B, 256, 0, stream>>>(entMentIndex, entMentLent, input_data, word_embed, featb, f1b);

    // fm = f1 @ h_m  (M=4096, N=128, K=320)
    k_mfma<3><<<dim3(FMS / 64, B / 128), 256, 0, stream>>>(f1b, F1S, h_mt, F1S, fm, FMS, F1S, nullptr);

    // persistent fused BiLSTM (all 10 steps, 4 instances; 512 blocks = 2/CU)
    k_lstm<<<512, 512, 0, stream>>>(xb, Wcat, biasb, ctxLeftLent, ctxRightLent, ctxb);

    // scores = relu(ctx@h1 + fm)@h2   (M=81920, N=128 full, K=448)
    k_attsc<<<MX / 128, 256, 0, stream>>>(ctxb, h1t, fm, h2, scores);
    // softmax + weighted sum -> featb[:,300:700]
    k_att2<<<B, 256, 0, stream>>>(scores, ctxb, featb);

    // ent = relu(feat @ dense_W + b)  (M=4096, N=256, K=704)
    k_mfma<1><<<dim3(TD / 64, B / 128), 256, 0, stream>>>(featb, FBS, dWt, FBS,
                                                          ent, TD, FBS, dense_b);
    k_l2norm<<<B, 256, 0, stream>>>(ent, TD);
    k_typenorm<<<NTY, TD, 0, stream>>>(type_path, type_tok, tnorm);
    k_final<<<B, 128, 0, stream>>>(ent, tnorm, out);
}

// Round 19
// 542.078 us; speedup vs baseline: 1.0558x; 1.0558x over previous
//
#include <hip/hip_runtime.h>
#include <hip/hip_bf16.h>

// Problem constants
constexpr int B    = 4096;
constexpr int T    = 80;
constexpr int CTXN = 10;
constexpr int D    = 300;
constexpr int R    = 200;
constexpr int HA   = 100;
constexpr int TD   = 256;
constexpr int NTY  = 113;
constexpr int PL   = 3;
constexpr int NTOK = 250;
constexpr int CTX2 = 20;    // 2*CTX
constexpr int R2   = 400;   // 2R
constexpr int FEAT = 700;   // D + 2R

// padded layout constants
constexpr int XSB  = 320;   // x row stride (300 pad to 320)
constexpr int KH   = 256;   // h part of concat K (200 pad to 256)
constexpr int KW   = 576;   // total gate-GEMM K: [Wh 0..255 | Wx 256..575]
constexpr int NB   = 832;   // bundled gate cols: 13 rb * 64 (4 gates x 16 r)
constexpr int CTXS = 448;   // ctx row stride: [dir0 0..223 | dir1 224..447]
constexpr int DREG = 224;   // per-dir region width (cols)
constexpr int F1S  = 320;   // f1 row stride
constexpr int FBS  = 704;   // feat row stride (700 -> 704)
constexpr int FMS  = 128;   // fm col stride (100 -> 128)
constexpr int MX   = 2 * B * CTXN;  // 81920 x-rows (side-major)

typedef __attribute__((ext_vector_type(8))) short bf16x8;
typedef __attribute__((ext_vector_type(4))) float f32x4;

__device__ __forceinline__ ushort f2bf(float f) {
    union { float f; uint32_t u; } x{f};
    uint32_t r = x.u + 0x7fff + ((x.u >> 16) & 1);
    return (ushort)(r >> 16);
}
__device__ __forceinline__ float bf2f(ushort u) {
    union { uint32_t u; float f; } x{(uint32_t)u << 16};
    return x.f;
}
// fast sigmoid/tanh via v_exp_f32 + v_rcp_f32 (exact at saturation)
__device__ __forceinline__ float fsig(float x) {
    return __builtin_amdgcn_rcpf(1.f + __expf(-x));
}
__device__ __forceinline__ float ftanh(float x) {
    return 1.f - 2.f * __builtin_amdgcn_rcpf(__expf(2.f * x) + 1.f);
}

#define GLD_LDS(g, l) __builtin_amdgcn_global_load_lds( \
    (const __attribute__((address_space(1))) void*)(g), \
    (__attribute__((address_space(3))) void*)(l), 16, 0, 0)
// NT variant: single-touch streams must not evict L2-resident weights
#define GLD_LDS_NT(g, l) __builtin_amdgcn_global_load_lds( \
    (const __attribute__((address_space(1))) void*)(g), \
    (__attribute__((address_space(3))) void*)(l), 16, 0, 2)

// ---------------------------------------------------------------------------
// weight prep: Wcat[dir][n' 832][k 576] bf16 (k = [Wh 256 | Wx 320]) + bias
// n' = rb*64 + g*16 + ri  <->  original gate col = g*200 + rb*16 + ri
constexpr int NWC = 2 * NB * KW;
__global__ void k_prepw3(const float* __restrict__ Wx_f, const float* __restrict__ Wh_f,
                         const float* __restrict__ bf_, const float* __restrict__ Wx_b,
                         const float* __restrict__ Wh_b, const float* __restrict__ bb_,
                         ushort* __restrict__ Wcat, float* __restrict__ biasb) {
    int gid = blockIdx.x * blockDim.x + threadIdx.x;
    if (gid < NWC) {
        int k = gid % KW;
        int q = gid / KW;
        int np = q % NB, dir = q / NB;
        int rb = np >> 6, g = (np >> 4) & 3, ri = np & 15;
        int r = rb * 16 + ri, col = g * 200 + r;
        float v = 0.f;
        if (r < R) {
            if (k < KH) {
                if (k < R) v = (dir ? Wh_b : Wh_f)[(size_t)k * 800 + col];
            } else {
                int kx = k - KH;
                if (kx < D) v = (dir ? Wx_b : Wx_f)[(size_t)kx * 800 + col];
            }
        }
        Wcat[gid] = f2bf(v);
    } else if (gid < NWC + 2 * NB) {
        int t = gid - NWC;
        int np = t % NB, dirb = t / NB;
        int rb = np >> 6, g = (np >> 4) & 3, ri = np & 15;
        int r = rb * 16 + ri, col = g * 200 + r;
        biasb[t] = (r < R) ? (dirb ? bb_ : bf_)[col] : 0.f;
    }
}

// h1t[n 128][k 448] — dual-region ctx layout:
// ctx col c<224 -> h1 row c (c<200), c>=224 -> h1 row 200+(c-224) (c-224<200)
__global__ void k_preph1(const float* __restrict__ h1, ushort* __restrict__ h1t) {
    int gid = blockIdx.x * blockDim.x + threadIdx.x;
    if (gid >= FMS * CTXS) return;
    int k = gid % CTXS, n = gid / CTXS;
    float v = 0.f;
    if (n < HA) {
        if (k < DREG) {
            if (k < R) v = h1[(size_t)k * HA + n];
        } else {
            int r2 = k - DREG;
            if (r2 < R) v = h1[(size_t)(R + r2) * HA + n];
        }
    }
    h1t[gid] = f2bf(v);
}
// h_mt[n 128][k 320]
__global__ void k_prephm(const float* __restrict__ h_m, ushort* __restrict__ h_mt) {
    int gid = blockIdx.x * blockDim.x + threadIdx.x;
    if (gid >= FMS * F1S) return;
    int k = gid % F1S, n = gid / F1S;
    float v = (n < HA && k < D) ? h_m[(size_t)k * HA + n] : 0.f;
    h_mt[gid] = f2bf(v);
}
// dWt[n 256][k 704]
__global__ void k_prepdw(const float* __restrict__ dW, ushort* __restrict__ dWt) {
    int gid = blockIdx.x * blockDim.x + threadIdx.x;
    if (gid >= TD * FBS) return;
    int k = gid % FBS, n = gid / FBS;
    float v = (k < FEAT) ? dW[(size_t)k * TD + n] : 0.f;
    dWt[gid] = f2bf(v);
}

// ---------------------------------------------------------------------------
// gather context word vectors -> xb[row = side*40960 + b*10 + t][320] bf16
__global__ void k_gatherb(const int* __restrict__ idxL, const int* __restrict__ idxR,
                          const int* __restrict__ input_data,
                          const float* __restrict__ we,
                          ushort* __restrict__ xb) {
    int row = blockIdx.x * 4 + (threadIdx.x >> 6);
    int lane = threadIdx.x & 63;
    if (row >= MX) return;
    int side = row / (B * CTXN);
    int bt = row % (B * CTXN);
    int idx = (side ? idxR : idxL)[bt];
    int w = (idx >= 0 && idx < B * T) ? input_data[idx] : -1;
    ushort* dst = xb + (size_t)row * XSB;
    if (lane < XSB / 8) {
        int e0 = lane * 8;
        ushort tmp[8];
        #pragma unroll
        for (int j = 0; j < 8; ++j) {
            int e = e0 + j;
            float f = (w >= 0 && e < D) ? we[(size_t)w * D + e] : 0.f;
            tmp[j] = f2bf(f);
        }
        *reinterpret_cast<bf16x8*>(dst + e0) = *reinterpret_cast<bf16x8*>(tmp);
    }
}

// ---------------------------------------------------------------------------
// f1 = mean of mention vectors -> featb[:,0:300] and f1b[:,0:320] (bf16)
__global__ void k_f1(const int* __restrict__ ment_idx,
                     const float* __restrict__ ment_lent,
                     const int* __restrict__ input_data,
                     const float* __restrict__ we,
                     ushort* __restrict__ featb, ushort* __restrict__ f1b) {
    int b = blockIdx.x;
    __shared__ int wrow[5];
    if (threadIdx.x < 5) {
        int idx = ment_idx[b * 5 + threadIdx.x];
        wrow[threadIdx.x] = (idx >= 0 && idx < B * T) ? input_data[idx] : -1;
    }
    __syncthreads();
    float inv = 1.0f / ment_lent[b];
    for (int d = threadIdx.x; d < F1S; d += blockDim.x) {
        float s = 0.f;
        if (d < D) {
            #pragma unroll
            for (int j = 0; j < 5; ++j) {
                int w = wrow[j];
                if (w >= 0) s += we[(size_t)w * D + d];
            }
            s *= inv;
        }
        ushort u = f2bf(s);
        if (d < D) featb[(size_t)b * FBS + d] = u;
        f1b[(size_t)b * F1S + d] = u;
    }
}

// ---------------------------------------------------------------------------
// Generic MFMA GEMM: C[M x N] = epi(A[M x K]bf16 @ Bt[N x K]bf16^T)
// BM=128, BN=64, BK=64.  MODE 1: bias+relu -> fp32.  MODE 3: plain fp32.
template<int MODE>
__global__ __launch_bounds__(256) void k_mfma(
    const ushort* __restrict__ A, int lda,
    const ushort* __restrict__ Bt, int ldb,
    float* __restrict__ C, int ldc, int K,
    const float* __restrict__ aux) {
    __shared__ __align__(16) ushort As[128 * 64];
    __shared__ __align__(16) ushort Bs[64 * 64];
    int tid = threadIdx.x, wave = tid >> 6, lane = tid & 63;
    int m0 = blockIdx.y * 128, n0 = blockIdx.x * 64;
    int wr = wave >> 1, wc = wave & 1;
    f32x4 acc[4][2] = {};

    for (int k0 = 0; k0 < K; k0 += 64) {
        #pragma unroll
        for (int p = 0; p < 4; ++p) {
            int chunk = p * 4 + wave;
            int row = chunk * 8 + (lane >> 3);
            int ss = (lane & 7) ^ (row & 7);
            GLD_LDS(A + (size_t)(m0 + row) * lda + k0 + ss * 8, As + chunk * 512);
        }
        #pragma unroll
        for (int p = 0; p < 2; ++p) {
            int chunk = p * 4 + wave;
            int row = chunk * 8 + (lane >> 3);
            int ss = (lane & 7) ^ (row & 7);
            GLD_LDS(Bt + (size_t)(n0 + row) * ldb + k0 + ss * 8, Bs + chunk * 512);
        }
        __syncthreads();
        #pragma unroll
        for (int kk = 0; kk < 2; ++kk) {
            bf16x8 a[4], bf[2];
            #pragma unroll
            for (int m = 0; m < 4; ++m) {
                int r = wr * 64 + m * 16 + (lane & 15);
                int ss = (kk * 4 + (lane >> 4)) ^ (r & 7);
                a[m] = *(const bf16x8*)&As[r * 64 + ss * 8];
            }
            #pragma unroll
            for (int n = 0; n < 2; ++n) {
                int r = wc * 32 + n * 16 + (lane & 15);
                int ss = (kk * 4 + (lane >> 4)) ^ (r & 7);
                bf[n] = *(const bf16x8*)&Bs[r * 64 + ss * 8];
            }
            #pragma unroll
            for (int m = 0; m < 4; ++m)
                #pragma unroll
                for (int n = 0; n < 2; ++n)
                    acc[m][n] = __builtin_amdgcn_mfma_f32_16x16x32_bf16(a[m], bf[n], acc[m][n], 0, 0, 0);
        }
        __syncthreads();
    }
    #pragma unroll
    for (int m = 0; m < 4; ++m) {
        #pragma unroll
        for (int n = 0; n < 2; ++n) {
            int c = n0 + wc * 32 + n * 16 + (lane & 15);
            #pragma unroll
            for (int j = 0; j < 4; ++j) {
                int rr = m0 + wr * 64 + m * 16 + (lane >> 4) * 4 + j;
                float v = acc[m][n][j];
                if (MODE == 1) v = fmaxf(v + aux[c], 0.f);
                C[(size_t)rr * ldc + c] = v;
            }
        }
    }
}

// ---------------------------------------------------------------------------
// Persistent fused BiLSTM: 256 blocks (1/CU) x 1024 threads (16 waves).
// Best-measured configuration (r15, 542 us total): waves 0..12 each own one
// rb; 4 waves/SIMD hide weight-tile latency. Weight staging: 2KB half-tiles
// in a 3-deep rotating LDS ring. Dir-segregated XCD mapping + dual-region
// ctx keep weights L2-resident per XCD; NT x staging; fast cell math.
// Note: allocator pins 64 VGPR at this shape (acc spills to scratch) but
// the 4-wave/SIMD latency hiding outweighs the spill traffic — measured
// faster than all non-spilling variants (542 vs 555/561/572).
#define WISSUE(KT2, HF2) { \
    ushort* dst = &wS[wave][(2 * (KT2) + (HF2)) % 3][0]; \
    _Pragma("unroll") for (int i = 0; i < 2; ++i) { \
        int p = i * 64 + lane; \
        int nl = p >> 2, c8s = p & 3; \
        int c8 = c8s ^ ((nl >> 1) & 3); \
        GLD_LDS(wb + (size_t)((HF2) * 32 + nl) * KW + (KT2) * 32 + c8 * 8, dst + i * 512); \
    } }

__global__ __launch_bounds__(1024)
__attribute__((amdgpu_waves_per_eu(4, 4)))
void k_lstm(
    const ushort* __restrict__ xb,       // [MX][320]
    const ushort* __restrict__ Wcat,     // [2][832][576]
    const float* __restrict__ biasb,     // [2][832]
    const float* __restrict__ lentL, const float* __restrict__ lentR,
    ushort* __restrict__ ctxb) {         // [B][20][448] dual-region
    __shared__ __align__(16) ushort hS[64 * 256];      // 32K swizzled h state
    __shared__ __align__(16) ushort xS[64 * 320];      // 40K swizzled x tile
    __shared__ __align__(16) ushort wS[13][3][1024];   // 78K per-rb W half-tile ring
    __shared__ int lenS[64];
    __shared__ int xrowS[CTXN][64];

    const int tid = threadIdx.x, wave = tid >> 6, lane = tid & 63;
    const int bid = blockIdx.x, xcd = bid & 7;
    const int dir = xcd >> 2;                     // XCD 0-3 -> dir0, 4-7 -> dir1
    const int idx = (xcd & 3) * 32 + (bid >> 3);  // bijective [0,128) per dir
    const int side = idx >> 6, rg = idx & 63;
    const int b0 = rg * 64;
    const ushort* Wd = Wcat + (size_t)dir * NB * KW;
    const int rl = lane & 15, ch = lane >> 4;
    const bool gw = (wave < 13);
    const ushort* wb = gw ? (Wd + (size_t)wave * 64 * KW) : Wd;

    if (tid < 64) {
        int b = b0 + tid;
        int len = (int)((side ? lentR : lentL)[b]);
        len = min(max(len, 0), CTXN);
        lenS[tid] = len;
        for (int s = 0; s < CTXN; ++s) {
            int tt = dir ? ((s < len) ? (len - 1 - s) : s) : s;
            xrowS[s][tid] = (side * (B * CTXN) + b * CTXN + tt) * XSB;
        }
    }
    // zero h state
    {
        uint4 zz{0, 0, 0, 0};
        for (int i = tid; i < 64 * 256 / 8; i += 1024)
            reinterpret_cast<uint4*>(hS)[i] = zz;
    }

    float bias_[4];
    #pragma unroll
    for (int g = 0; g < 4; ++g)
        bias_[g] = gw ? biasb[dir * NB + wave * 64 + g * 16 + rl] : 0.f;
    float cst[16];
    #pragma unroll
    for (int j = 0; j < 16; ++j) cst[j] = 0.f;

    __syncthreads();

    // stage x tile for s=0 (pre-swizzled global source, linear LDS dest, NT)
    for (int c2 = wave; c2 < 40; c2 += 16) {
        int p = c2 * 64 + lane;
        int row = p / 40, c8s = p - row * 40;
        int c8 = c8s ^ (row & 7);
        GLD_LDS_NT(xb + xrowS[0][row] + c8 * 8, xS + c2 * 512);
    }
    __syncthreads();

    for (int s = 0; s < CTXN; ++s) {
        const int ktstart = (s == 0) ? 8 : 0;   // h == 0 at s=0: skip Wh part
        f32x4 acc[4][4] = {};
        if (gw) {
            // prologue: first 3 half-tiles
            WISSUE(ktstart, 0);
            WISSUE(ktstart, 1);
            WISSUE(ktstart + 1, 0);
            bf16x8 af[4];
            for (int kt = ktstart; kt < 18; ++kt) {
                // A fragments for this kt (shared by both halves)
                {
                    const ushort* abase; int astr, kof;
                    if (kt < 8) { abase = hS; astr = 256; kof = kt * 4; }
                    else        { abase = xS; astr = 320; kof = (kt - 8) * 4; }
                    #pragma unroll
                    for (int m = 0; m < 4; ++m) {
                        int row = m * 16 + rl;
                        int g = (kof + ch) ^ (row & 7);
                        af[m] = *reinterpret_cast<const bf16x8*>(&abase[row * astr + g * 8]);
                    }
                }
                const int c8r = ch ^ ((rl >> 1) & 3);
                // ---- half 0 (cols 0..31 -> acc[.][0..1]) ----
                if (kt < 17) { asm volatile("s_waitcnt vmcnt(4)" ::: "memory"); }
                else         { asm volatile("s_waitcnt vmcnt(2)" ::: "memory"); }
                {
                    const ushort* wbuf = &wS[wave][(2 * kt) % 3][0];
                    bf16x8 b0 = *reinterpret_cast<const bf16x8*>(&wbuf[(rl) * 32 + c8r * 8]);
                    bf16x8 b1 = *reinterpret_cast<const bf16x8*>(&wbuf[(16 + rl) * 32 + c8r * 8]);
                    if (kt + 1 < 18) WISSUE(kt + 1, 1);
                    #pragma unroll
                    for (int m = 0; m < 4; ++m) {
                        acc[m][0] = __builtin_amdgcn_mfma_f32_16x16x32_bf16(af[m], b0, acc[m][0], 0, 0, 0);
                        acc[m][1] = __builtin_amdgcn_mfma_f32_16x16x32_bf16(af[m], b1, acc[m][1], 0, 0, 0);
                    }
                }
                // ---- half 1 (cols 32..63 -> acc[.][2..3]) ----
                if (kt < 17) { asm volatile("s_waitcnt vmcnt(4)" ::: "memory"); }
                else         { asm volatile("s_waitcnt vmcnt(0)" ::: "memory"); }
                {
                    const ushort* wbuf = &wS[wave][(2 * kt + 1) % 3][0];
                    bf16x8 b0 = *reinterpret_cast<const bf16x8*>(&wbuf[(rl) * 32 + c8r * 8]);
                    bf16x8 b1 = *reinterpret_cast<const bf16x8*>(&wbuf[(16 + rl) * 32 + c8r * 8]);
                    if (kt + 2 < 18) WISSUE(kt + 2, 0);
                    #pragma unroll
                    for (int m = 0; m < 4; ++m) {
                        acc[m][2] = __builtin_amdgcn_mfma_f32_16x16x32_bf16(af[m], b0, acc[m][2], 0, 0, 0);
                        acc[m][3] = __builtin_amdgcn_mfma_f32_16x16x32_bf16(af[m], b1, acc[m][3], 0, 0, 0);
                    }
                }
            }
        }
        // barrier1: all LDS reads of hS/xS complete (GEMM done)
        asm volatile("s_waitcnt lgkmcnt(0)" ::: "memory");
        __builtin_amdgcn_s_barrier();

        // cell (register-only) + write h -> hS (masked) + stage -> wS[wave][0]
        if (gw) {
            const int r = wave * 16 + rl;
            #pragma unroll
            for (int m = 0; m < 4; ++m) {
                #pragma unroll
                for (int j = 0; j < 4; ++j) {
                    int row = m * 16 + ch * 4 + j;
                    float gi = acc[m][0][j] + bias_[0];
                    float gf = acc[m][1][j] + bias_[1];
                    float gg = acc[m][2][j] + bias_[2];
                    float go = acc[m][3][j] + bias_[3];
                    float si = fsig(gi), sf = fsig(gf), so = fsig(go);
                    float cn = sf * cst[m * 4 + j] + si * ftanh(gg);
                    float hn = so * ftanh(cn);
                    bool live = (s < lenS[row]);
                    if (live) cst[m * 4 + j] = cn;
                    ushort hv = f2bf(live ? hn : 0.f);
                    wS[wave][0][row * 16 + rl] = hv;
                    if (live && r < R)
                        hS[row * 256 + (((r >> 3) ^ (row & 7)) << 3) + (r & 7)] = hv;
                }
            }
        }
        // stage x tile for next step (NT; in flight until barrier3)
        if (s + 1 < CTXN) {
            for (int c2 = wave; c2 < 40; c2 += 16) {
                int p = c2 * 64 + lane;
                int row = p / 40, c8s = p - row * 40;
                int c8 = c8s ^ (row & 7);
                GLD_LDS_NT(xb + xrowS[s + 1][row] + c8 * 8, xS + c2 * 512);
            }
        }
        // barrier2: stage + hS visible (x loads may still be in flight)
        asm volatile("s_waitcnt lgkmcnt(0)" ::: "memory");
        __builtin_amdgcn_s_barrier();

        // cooperative ctx write: 64 rows x 28 granules of 16B into this dir's
        // 448B-aligned region; granules 26/27 (cols 208-223) are pad zeros.
        for (int i = tid; i < 64 * 28; i += 1024) {
            int row = i / 28, g = i - row * 28;
            int len = lenS[row];
            int tp = (s < len) ? (dir ? (len - 1 - s) : s) : s;
            bf16x8 v{};
            if (g < 26) {
                int rb2 = g >> 1;
                int off = (g & 1) * 8;
                v = *reinterpret_cast<const bf16x8*>(&wS[rb2][0][row * 16 + off]);
            }
            *reinterpret_cast<bf16x8*>(
                ctxb + ((size_t)(b0 + row) * CTX2 + side * CTXN + tp) * CTXS + dir * DREG + g * 8) = v;
        }
        // barrier3: full drain (x staged, stores issued, wS free for reuse)
        asm volatile("s_waitcnt vmcnt(0) lgkmcnt(0)" ::: "memory");
        __builtin_amdgcn_s_barrier();
    }
}

// ---------------------------------------------------------------------------
// att-score GEMM: scores[row] = relu(ctx[row]@h1 + fm[row/20]) . h2
// grid (MX/128), BM=128, BN=128(full), K=448  (dual-region K handled by h1t)
__global__ __launch_bounds__(256) void k_attsc(
    const ushort* __restrict__ ctxb, const ushort* __restrict__ h1t,
    const float* __restrict__ fm, const float* __restrict__ h2,
    float* __restrict__ scores) {
    __shared__ __align__(16) ushort As[128 * 64];
    __shared__ __align__(16) ushort Bs[128 * 64];
    __shared__ float sred[128][2];
    __shared__ float h2s[128];
    int tid = threadIdx.x, wave = tid >> 6, lane = tid & 63;
    int m0 = blockIdx.x * 128;
    if (tid < 128) h2s[tid] = (tid < HA) ? h2[tid] : 0.f;
    int wr = wave >> 1, wc = wave & 1;
    f32x4 acc[4][4] = {};

    for (int k0 = 0; k0 < CTXS; k0 += 64) {
        #pragma unroll
        for (int p = 0; p < 4; ++p) {
            int chunk = p * 4 + wave;
            int row = chunk * 8 + (lane >> 3);
            int ss = (lane & 7) ^ (row & 7);
            GLD_LDS(ctxb + (size_t)(m0 + row) * CTXS + k0 + ss * 8, As + chunk * 512);
        }
        #pragma unroll
        for (int p = 0; p < 4; ++p) {
            int chunk = p * 4 + wave;
            int row = chunk * 8 + (lane >> 3);
            int ss = (lane & 7) ^ (row & 7);
            GLD_LDS(h1t + (size_t)row * CTXS + k0 + ss * 8, Bs + chunk * 512);
        }
        __syncthreads();
        #pragma unroll
        for (int kk = 0; kk < 2; ++kk) {
            bf16x8 a[4], bf[4];
            #pragma unroll
            for (int m = 0; m < 4; ++m) {
                int r = wr * 64 + m * 16 + (lane & 15);
                int ss = (kk * 4 + (lane >> 4)) ^ (r & 7);
                a[m] = *(const bf16x8*)&As[r * 64 + ss * 8];
            }
            #pragma unroll
            for (int n = 0; n < 4; ++n) {
                int r = wc * 64 + n * 16 + (lane & 15);
                int ss = (kk * 4 + (lane >> 4)) ^ (r & 7);
                bf[n] = *(const bf16x8*)&Bs[r * 64 + ss * 8];
            }
            #pragma unroll
            for (int m = 0; m < 4; ++m)
                #pragma unroll
                for (int n = 0; n < 4; ++n)
                    acc[m][n] = __builtin_amdgcn_mfma_f32_16x16x32_bf16(a[m], bf[n], acc[m][n], 0, 0, 0);
        }
        __syncthreads();
    }
    #pragma unroll
    for (int m = 0; m < 4; ++m) {
        #pragma unroll
        for (int j = 0; j < 4; ++j) {
            int rl = wr * 64 + m * 16 + (lane >> 4) * 4 + j;
            int brow = (m0 + rl) / CTX2;
            float v = 0.f;
            #pragma unroll
            for (int n = 0; n < 4; ++n) {
                int c = wc * 64 + n * 16 + (lane & 15);
                float a = acc[m][n][j] + fm[(size_t)brow * FMS + c];
                v += fmaxf(a, 0.f) * h2s[c];
            }
            #pragma unroll
            for (int o = 1; o < 16; o <<= 1) v += __shfl_xor(v, o, 64);
            if ((lane & 15) == 0) sred[rl][wc] = v;
        }
    }
    __syncthreads();
    if (tid < 128) scores[m0 + tid] = sred[tid][0] + sred[tid][1];
}

// ---------------------------------------------------------------------------
// softmax over 20 scores + weighted ctx sum -> featb[:,300:700] (+pad zero)
// ctx col c<200 at region pos c; c>=200 at pos 224+(c-200)
__global__ void k_att2(const float* __restrict__ scores,
                       const ushort* __restrict__ ctxb,
                       ushort* __restrict__ featb) {
    int b = blockIdx.x;
    float sc[CTX2];
    #pragma unroll
    for (int t = 0; t < CTX2; ++t) sc[t] = scores[b * CTX2 + t];
    float mx = -1e30f;
    #pragma unroll
    for (int t = 0; t < CTX2; ++t) mx = fmaxf(mx, sc[t]);
    float w[CTX2], sum = 0.f;
    #pragma unroll
    for (int t = 0; t < CTX2; ++t) { w[t] = __expf(sc[t] - mx); sum += w[t]; }
    float inv = 1.f / sum;
    for (int col = threadIdx.x; col < R2; col += 256) {
        int pos = (col < R) ? col : col + (DREG - R);
        float acc = 0.f;
        #pragma unroll
        for (int t = 0; t < CTX2; ++t)
            acc += w[t] * bf2f(ctxb[((size_t)b * CTX2 + t) * CTXS + pos]);
        featb[(size_t)b * FBS + D + col] = f2bf(acc * inv);
    }
    if (threadIdx.x < FBS - FEAT)
        featb[(size_t)b * FBS + FEAT + threadIdx.x] = 0;
}

// ---------------------------------------------------------------------------
__device__ __forceinline__ float blk_sum_256(float v, float* red) {
    #pragma unroll
    for (int o = 32; o > 0; o >>= 1) v += __shfl_down(v, o, 64);
    int lane = threadIdx.x & 63, wid = threadIdx.x >> 6;
    if (lane == 0) red[wid] = v;
    __syncthreads();
    float t = red[0] + red[1] + red[2] + red[3];
    __syncthreads();
    return t;
}

__global__ void k_l2norm(float* __restrict__ x, int ncol) {
    int row = blockIdx.x;
    float* p = x + (size_t)row * ncol;
    __shared__ float red[4];
    float ss = 0.f;
    for (int c = threadIdx.x; c < ncol; c += 256) { float v = p[c]; ss += v * v; }
    float tot = blk_sum_256(ss, red);
    float scale = 1.f / sqrtf(fmaxf(tot, 1e-12f));
    for (int c = threadIdx.x; c < ncol; c += 256) p[c] *= scale;
}

__global__ void k_typenorm(const int* __restrict__ type_path,
                           const float* __restrict__ type_tok,
                           float* __restrict__ tnorm) {
    int y = blockIdx.x;
    int c = threadIdx.x;
    __shared__ float red[4];
    float s = 0.f;
    #pragma unroll
    for (int j = 0; j < PL; ++j) {
        int tk = type_path[y * PL + j];
        if (tk >= 0 && tk < NTOK) s += type_tok[(size_t)tk * TD + c];
    }
    float tot = blk_sum_256(s * s, red);
    float scale = 1.f / sqrtf(fmaxf(tot, 1e-12f));
    tnorm[(size_t)y * TD + c] = s * scale;
}

__global__ void k_final(const float* __restrict__ ent,
                        const float* __restrict__ tnorm,
                        float* __restrict__ out) {
    int b = blockIdx.x;
    __shared__ float es[TD];
    for (int c = threadIdx.x; c < TD; c += blockDim.x) es[c] = ent[(size_t)b * TD + c];
    __syncthreads();
    for (int y = threadIdx.x; y < NTY; y += blockDim.x) {
        const float* tn = tnorm + (size_t)y * TD;
        float acc = 0.f;
        #pragma unroll 4
        for (int k = 0; k < TD; ++k) acc += es[k] * tn[k];
        out[(size_t)b * NTY + y] = acc;
    }
}

// ---------------------------------------------------------------------------
static inline char* wsalloc(char*& p, size_t bytes) {
    char* r = p;
    p += (bytes + 255) & ~(size_t)255;
    return r;
}

extern "C" void kernel_launch(void* const* d_in, const int* in_sizes, int n_in,
                              void* d_out, int out_size, void* d_ws, size_t ws_size,
                              hipStream_t stream) {
    const int*   input_data       = (const int*)d_in[0];
    const int*   entMentIndex     = (const int*)d_in[1];
    const int*   entCtxLeftIndex  = (const int*)d_in[2];
    const int*   entCtxRightIndex = (const int*)d_in[3];
    const float* entMentLent      = (const float*)d_in[4];
    const float* ctxLeftLent      = (const float*)d_in[5];
    const float* ctxRightLent     = (const float*)d_in[6];
    const int*   type_path        = (const int*)d_in[7];
    const float* word_embed       = (const float*)d_in[8];
    const float* h_m              = (const float*)d_in[9];
    const float* h1               = (const float*)d_in[10];
    const float* h2               = (const float*)d_in[11];
    const float* Wx_f             = (const float*)d_in[12];
    const float* Wh_f             = (const float*)d_in[13];
    const float* b_f              = (const float*)d_in[14];
    const float* Wx_b             = (const float*)d_in[15];
    const float* Wh_b             = (const float*)d_in[16];
    const float* b_b              = (const float*)d_in[17];
    const float* dense_W          = (const float*)d_in[18];
    const float* dense_b          = (const float*)d_in[19];
    const float* type_tok         = (const float*)d_in[20];
    float* out = (float*)d_out;

    char* p = (char*)d_ws;
    ushort* xb    = (ushort*)wsalloc(p, (size_t)MX * XSB * 2);          // 52.4 MB
    ushort* ctxb  = (ushort*)wsalloc(p, (size_t)B * CTX2 * CTXS * 2);   // 73.4 MB
    ushort* featb = (ushort*)wsalloc(p, (size_t)B * FBS * 2);
    ushort* f1b   = (ushort*)wsalloc(p, (size_t)B * F1S * 2);
    float*  fm    = (float*) wsalloc(p, (size_t)B * FMS * 4);
    float*  scores= (float*) wsalloc(p, (size_t)MX * 4);
    float*  ent   = (float*) wsalloc(p, (size_t)B * TD * 4);
    float*  tnorm = (float*) wsalloc(p, (size_t)NTY * TD * 4);
    ushort* Wcat  = (ushort*)wsalloc(p, (size_t)2 * NB * KW * 2);       // 1.9 MB
    float*  biasb = (float*) wsalloc(p, (size_t)2 * NB * 4);
    ushort* h1t   = (ushort*)wsalloc(p, (size_t)FMS * CTXS * 2);
    ushort* h_mt  = (ushort*)wsalloc(p, (size_t)FMS * F1S * 2);
    ushort* dWt   = (ushort*)wsalloc(p, (size_t)TD * FBS * 2);

    // weight prep (no memsets — all consumed buffers fully written)
    {
        int tot = NWC + 2 * NB;
        k_prepw3<<<(tot + 255) / 256, 256, 0, stream>>>(Wx_f, Wh_f, b_f, Wx_b, Wh_b, b_b,
                                                        Wcat, biasb);
    }
    k_preph1<<<(FMS * CTXS + 255) / 256, 256, 0, stream>>>(h1, h1t);
    k_prephm<<<(FMS * F1S + 255) / 256, 256, 0, stream>>>(h_m, h_mt);
    k_prepdw<<<(TD * FBS + 255) / 256, 256, 0, stream>>>(dense_W, dWt);

    // gathers + f1
    k_gatherb<<<(MX + 3) / 4, 256, 0, stream>>>(entCtxLeftIndex, entCtxRightIndex,
                                                input_data, word_embed, xb);
    k_f1<<<B, 256, 0, stream>>>(entMentIndex, entMentLent, input_data, word_embed, featb, f1b);

    // fm = f1 @ h_m  (M=4096, N=128, K=320)
    k_mfma<3><<<dim3(FMS / 64, B / 128), 256, 0, stream>>>(f1b, F1S, h_mt, F1S, fm, FMS, F1S, nullptr);

    // persistent fused BiLSTM (all 10 steps, 4 instances)
    k_lstm<<<256, 1024, 0, stream>>>(xb, Wcat, biasb, ctxLeftLent, ctxRightLent, ctxb);

    // scores = relu(ctx@h1 + fm)@h2   (M=81920, N=128 full, K=448)
    k_attsc<<<MX / 128, 256, 0, stream>>>(ctxb, h1t, fm, h2, scores);
    // softmax + weighted sum -> featb[:,300:700]
    k_att2<<<B, 256, 0, stream>>>(scores, ctxb, featb);

    // ent = relu(feat @ dense_W + b)  (M=4096, N=256, K=704)
    k_mfma<1><<<dim3(TD / 64, B / 128), 256, 0, stream>>>(featb, FBS, dWt, FBS,
                                                          ent, TD, FBS, dense_b);
    k_l2norm<<<B, 256, 0, stream>>>(ent, TD);
    k_typenorm<<<NTY, TD, 0, stream>>>(type_path, type_tok, tnorm);
    k_final<<<B, 128, 0, stream>>>(ent, tnorm, out);
}